// Round 1
// baseline (8179.541 us; speedup 1.0000x reference)
//
#include <hip/hip_runtime.h>
#include <hip/hip_bf16.h>

// Problem constants
#define B_   1024
#define H_   512
#define L_   256
#define O_   128
#define SEQ_ 100
#define TE_  200

__device__ __forceinline__ float sigmoidf_(float x) { return 1.f / (1.f + __expf(-x)); }
__device__ __forceinline__ float tanhf_fast(float x) { return 1.f - 2.f / (__expf(2.f * x) + 1.f); }

// ---------------------------------------------------------------------------
// x0[j] = b_emb[j] + sum_o start[o] * W_emb[j,o]     (j < 512)
// ---------------------------------------------------------------------------
__global__ void k_x0(const float* __restrict__ start, const float* __restrict__ Wemb,
                     const float* __restrict__ bemb, float* __restrict__ x0) {
    int j = blockIdx.x * 256 + threadIdx.x;
    if (j < H_) {
        float s = bemb[j];
        const float* wp = Wemb + (size_t)j * O_;
        #pragma unroll 4
        for (int o = 0; o < O_; ++o) s += start[o] * wp[o];
        x0[j] = s;
    }
}

// ---------------------------------------------------------------------------
// Generic tiled fp32 GEMM: out[m,n] = act(bias[n] + A[m,:] . W[n,:])
// BM=BN=64, BK=16, 256 threads, 4x4 microtile. act: 0=none, 1=leaky_relu(0.01)
// ---------------------------------------------------------------------------
__global__ __launch_bounds__(256) void k_proj_act(
    const float* __restrict__ A, const float* __restrict__ W,
    const float* __restrict__ bias, float* __restrict__ out,
    int M, int N, int K, int act)
{
    __shared__ __align__(16) float As[16][68];
    __shared__ __align__(16) float Bs[16][68];
    const int tid = threadIdx.x;
    const int tx = tid & 15, ty = tid >> 4;
    const int m0 = blockIdx.y * 64, n0 = blockIdx.x * 64;
    float acc[4][4] = {};
    for (int kt = 0; kt < K; kt += 16) {
        int m = tid >> 2, k4 = (tid & 3) * 4;
        float4 av = *(const float4*)(A + (size_t)(m0 + m) * K + kt + k4);
        As[k4 + 0][m] = av.x; As[k4 + 1][m] = av.y; As[k4 + 2][m] = av.z; As[k4 + 3][m] = av.w;
        float4 bv = *(const float4*)(W + (size_t)(n0 + m) * K + kt + k4);
        Bs[k4 + 0][m] = bv.x; Bs[k4 + 1][m] = bv.y; Bs[k4 + 2][m] = bv.z; Bs[k4 + 3][m] = bv.w;
        __syncthreads();
        #pragma unroll
        for (int kk = 0; kk < 16; ++kk) {
            float4 a = *(const float4*)&As[kk][ty * 4];
            float4 b = *(const float4*)&Bs[kk][tx * 4];
            float aa[4] = {a.x, a.y, a.z, a.w}, bb[4] = {b.x, b.y, b.z, b.w};
            #pragma unroll
            for (int i = 0; i < 4; ++i)
                #pragma unroll
                for (int j = 0; j < 4; ++j) acc[i][j] += aa[i] * bb[j];
        }
        __syncthreads();
    }
    #pragma unroll
    for (int i = 0; i < 4; ++i) {
        int m = m0 + ty * 4 + i;
        #pragma unroll
        for (int j = 0; j < 4; ++j) {
            int n = n0 + tx * 4 + j;
            float v = acc[i][j] + bias[n];
            if (act == 1) v = v > 0.f ? v : 0.01f * v;
            out[(size_t)m * N + n] = v;
        }
    }
}

// ---------------------------------------------------------------------------
// Fused LSTM step: gates = relu(x) @ W_ih^T + h @ W_hh^T + b, then pointwise.
// Block tile: 64 batch rows x (16 j's x 4 gates = 64 cols). K = 1024 (two halves).
// Writes c (in-place), h_out, optional bf16 history.
// ---------------------------------------------------------------------------
__global__ __launch_bounds__(256) void k_lstm_step(
    const float* __restrict__ xsrc, int x_stride,
    const float* __restrict__ hsrc,
    const float* __restrict__ Wih, const float* __restrict__ Whh,
    const float* __restrict__ bih, const float* __restrict__ bhh,
    float* __restrict__ c, float* __restrict__ h_out,
    __hip_bfloat16* __restrict__ hist_t)
{
    __shared__ __align__(16) float smem[64 * 68];   // As[16][68] | Bs[16][68]; epilogue reuses as Gt[64][68]
    float* As = smem;
    float* Bs = smem + 16 * 68;
    const int tid = threadIdx.x;
    const int tx = tid & 15, ty = tid >> 4;
    const int m0 = blockIdx.y * 64;     // batch tile
    const int j0 = blockIdx.x * 16;     // j tile
    float acc[4][4] = {};
    for (int kt = 0; kt < 1024; kt += 16) {
        const bool first = kt < 512;
        const int k = first ? kt : kt - 512;
        int m = tid >> 2, k4 = (tid & 3) * 4;
        float4 av;
        if (first) {
            av = *(const float4*)(xsrc + (size_t)(m0 + m) * x_stride + k + k4);
            av.x = fmaxf(av.x, 0.f); av.y = fmaxf(av.y, 0.f);
            av.z = fmaxf(av.z, 0.f); av.w = fmaxf(av.w, 0.f);
        } else {
            av = *(const float4*)(hsrc + (size_t)(m0 + m) * H_ + k + k4);
        }
        As[(k4 + 0) * 68 + m] = av.x; As[(k4 + 1) * 68 + m] = av.y;
        As[(k4 + 2) * 68 + m] = av.z; As[(k4 + 3) * 68 + m] = av.w;
        int gate = m >> 4, jj = m & 15;
        const float* wp = (first ? Wih : Whh) + (size_t)(gate * H_ + j0 + jj) * H_ + k + k4;
        float4 bv = *(const float4*)wp;
        Bs[(k4 + 0) * 68 + m] = bv.x; Bs[(k4 + 1) * 68 + m] = bv.y;
        Bs[(k4 + 2) * 68 + m] = bv.z; Bs[(k4 + 3) * 68 + m] = bv.w;
        __syncthreads();
        #pragma unroll
        for (int kk = 0; kk < 16; ++kk) {
            float4 a = *(const float4*)&As[kk * 68 + ty * 4];
            float4 b = *(const float4*)&Bs[kk * 68 + tx * 4];
            float aa[4] = {a.x, a.y, a.z, a.w}, bb[4] = {b.x, b.y, b.z, b.w};
            #pragma unroll
            for (int i = 0; i < 4; ++i)
                #pragma unroll
                for (int j = 0; j < 4; ++j) acc[i][j] += aa[i] * bb[j];
        }
        __syncthreads();
    }
    // stash gate tile in LDS
    float* Gt = smem;  // [64 rows][68]
    #pragma unroll
    for (int i = 0; i < 4; ++i)
        #pragma unroll
        for (int j = 0; j < 4; ++j)
            Gt[(ty * 4 + i) * 68 + (tx * 4 + j)] = acc[i][j];
    __syncthreads();
    // pointwise LSTM: each thread handles 4 (row, jj) items with fixed jj = tid&15
    int jj = tid & 15;
    int j = j0 + jj;
    float bi = bih[0 * H_ + j] + bhh[0 * H_ + j];
    float bf = bih[1 * H_ + j] + bhh[1 * H_ + j];
    float bg = bih[2 * H_ + j] + bhh[2 * H_ + j];
    float bo = bih[3 * H_ + j] + bhh[3 * H_ + j];
    #pragma unroll
    for (int l = 0; l < 4; ++l) {
        int m = (tid >> 4) + l * 16;
        float iv = Gt[m * 68 + 0  + jj] + bi;
        float fv = Gt[m * 68 + 16 + jj] + bf;
        float gv = Gt[m * 68 + 32 + jj] + bg;
        float ov = Gt[m * 68 + 48 + jj] + bo;
        size_t off = (size_t)(m0 + m) * H_ + j;
        float cv = c[off];
        float cn = sigmoidf_(fv) * cv + sigmoidf_(iv) * tanhf_fast(gv);
        float hn = sigmoidf_(ov) * tanhf_fast(cn);
        c[off] = cn;
        h_out[off] = hn;
        if (hist_t) hist_t[off] = __float2bfloat16(hn);
    }
}

// ---------------------------------------------------------------------------
// Batched output projection: out[b, t, o] = b_out[o] + hist[t, b, :] . W_out[o, :]
// hist bf16 [SEQ, B, 512]; rows r = t*1024 + b; N=128; K=512.
// ---------------------------------------------------------------------------
__global__ __launch_bounds__(256) void k_out_proj(
    const __hip_bfloat16* __restrict__ hist,
    const float* __restrict__ Wout, const float* __restrict__ bout,
    float* __restrict__ out)
{
    __shared__ __align__(16) float As[16][68];
    __shared__ __align__(16) float Bs[16][68];
    const int tid = threadIdx.x;
    const int tx = tid & 15, ty = tid >> 4;
    const int m0 = blockIdx.y * 64, n0 = blockIdx.x * 64;
    float acc[4][4] = {};
    for (int kt = 0; kt < H_; kt += 16) {
        int m = tid >> 2, k4 = (tid & 3) * 4;
        uint2 r = *(const uint2*)(hist + (size_t)(m0 + m) * H_ + kt + k4);
        As[k4 + 0][m] = __uint_as_float(r.x << 16);
        As[k4 + 1][m] = __uint_as_float(r.x & 0xffff0000u);
        As[k4 + 2][m] = __uint_as_float(r.y << 16);
        As[k4 + 3][m] = __uint_as_float(r.y & 0xffff0000u);
        float4 bv = *(const float4*)(Wout + (size_t)(n0 + m) * H_ + kt + k4);
        Bs[k4 + 0][m] = bv.x; Bs[k4 + 1][m] = bv.y; Bs[k4 + 2][m] = bv.z; Bs[k4 + 3][m] = bv.w;
        __syncthreads();
        #pragma unroll
        for (int kk = 0; kk < 16; ++kk) {
            float4 a = *(const float4*)&As[kk][ty * 4];
            float4 b = *(const float4*)&Bs[kk][tx * 4];
            float aa[4] = {a.x, a.y, a.z, a.w}, bb[4] = {b.x, b.y, b.z, b.w};
            #pragma unroll
            for (int i = 0; i < 4; ++i)
                #pragma unroll
                for (int j = 0; j < 4; ++j) acc[i][j] += aa[i] * bb[j];
        }
        __syncthreads();
    }
    #pragma unroll
    for (int i = 0; i < 4; ++i) {
        int r = m0 + ty * 4 + i;
        int t = r >> 10, b = r & 1023;
        float4 v;
        v.x = acc[i][0] + bout[n0 + tx * 4 + 0];
        v.y = acc[i][1] + bout[n0 + tx * 4 + 1];
        v.z = acc[i][2] + bout[n0 + tx * 4 + 2];
        v.w = acc[i][3] + bout[n0 + tx * 4 + 3];
        *(float4*)(out + (size_t)b * (SEQ_ * O_) + t * O_ + n0 + tx * 4) = v;
    }
}

// ---------------------------------------------------------------------------
// Fallback per-step y projection (used only if ws too small for history).
// ---------------------------------------------------------------------------
__global__ __launch_bounds__(256) void k_y_step(
    const float* __restrict__ h, const float* __restrict__ Wout,
    const float* __restrict__ bout, float* __restrict__ out, int t)
{
    __shared__ __align__(16) float As[16][68];
    __shared__ __align__(16) float Bs[16][68];
    const int tid = threadIdx.x;
    const int tx = tid & 15, ty = tid >> 4;
    const int m0 = blockIdx.y * 64, n0 = blockIdx.x * 64;
    float acc[4][4] = {};
    for (int kt = 0; kt < H_; kt += 16) {
        int m = tid >> 2, k4 = (tid & 3) * 4;
        float4 av = *(const float4*)(h + (size_t)(m0 + m) * H_ + kt + k4);
        As[k4 + 0][m] = av.x; As[k4 + 1][m] = av.y; As[k4 + 2][m] = av.z; As[k4 + 3][m] = av.w;
        float4 bv = *(const float4*)(Wout + (size_t)(n0 + m) * H_ + kt + k4);
        Bs[k4 + 0][m] = bv.x; Bs[k4 + 1][m] = bv.y; Bs[k4 + 2][m] = bv.z; Bs[k4 + 3][m] = bv.w;
        __syncthreads();
        #pragma unroll
        for (int kk = 0; kk < 16; ++kk) {
            float4 a = *(const float4*)&As[kk][ty * 4];
            float4 b = *(const float4*)&Bs[kk][tx * 4];
            float aa[4] = {a.x, a.y, a.z, a.w}, bb[4] = {b.x, b.y, b.z, b.w};
            #pragma unroll
            for (int i = 0; i < 4; ++i)
                #pragma unroll
                for (int j = 0; j < 4; ++j) acc[i][j] += aa[i] * bb[j];
        }
        __syncthreads();
    }
    #pragma unroll
    for (int i = 0; i < 4; ++i) {
        int b = m0 + ty * 4 + i;
        float4 v;
        v.x = acc[i][0] + bout[n0 + tx * 4 + 0];
        v.y = acc[i][1] + bout[n0 + tx * 4 + 1];
        v.z = acc[i][2] + bout[n0 + tx * 4 + 2];
        v.w = acc[i][3] + bout[n0 + tx * 4 + 3];
        *(float4*)(out + (size_t)b * (SEQ_ * O_) + t * O_ + n0 + tx * 4) = v;
    }
}

// ---------------------------------------------------------------------------
// num head: out[r] = relu(b2 + sum_j w2[j] * lrelu(b_seq[j] + enc[r,:] . Wseq[j,:]))
// rows r = b*200 + t (204800). Block: 64 rows, loops all 8 chunks of 64 j.
// ---------------------------------------------------------------------------
__global__ __launch_bounds__(256) void k_num(
    const float* __restrict__ enc, const float* __restrict__ Wseq,
    const float* __restrict__ bseq, const float* __restrict__ w2,
    const float* __restrict__ b2, float* __restrict__ out)
{
    __shared__ __align__(16) float As[16][68];
    __shared__ __align__(16) float Bs[16][68];
    __shared__ float R[64][17];
    const int tid = threadIdx.x;
    const int tx = tid & 15, ty = tid >> 4;
    const int m0 = blockIdx.x * 64;
    float partial[4] = {0.f, 0.f, 0.f, 0.f};
    for (int n0 = 0; n0 < H_; n0 += 64) {
        float acc[4][4] = {};
        for (int kt = 0; kt < L_; kt += 16) {
            int m = tid >> 2, k4 = (tid & 3) * 4;
            float4 av = *(const float4*)(enc + (size_t)(m0 + m) * L_ + kt + k4);
            As[k4 + 0][m] = av.x; As[k4 + 1][m] = av.y; As[k4 + 2][m] = av.z; As[k4 + 3][m] = av.w;
            float4 bv = *(const float4*)(Wseq + (size_t)(n0 + m) * L_ + kt + k4);
            Bs[k4 + 0][m] = bv.x; Bs[k4 + 1][m] = bv.y; Bs[k4 + 2][m] = bv.z; Bs[k4 + 3][m] = bv.w;
            __syncthreads();
            #pragma unroll
            for (int kk = 0; kk < 16; ++kk) {
                float4 a = *(const float4*)&As[kk][ty * 4];
                float4 b = *(const float4*)&Bs[kk][tx * 4];
                float aa[4] = {a.x, a.y, a.z, a.w}, bb[4] = {b.x, b.y, b.z, b.w};
                #pragma unroll
                for (int i = 0; i < 4; ++i)
                    #pragma unroll
                    for (int j = 0; j < 4; ++j) acc[i][j] += aa[i] * bb[j];
            }
            __syncthreads();
        }
        #pragma unroll
        for (int i = 0; i < 4; ++i)
            #pragma unroll
            for (int j = 0; j < 4; ++j) {
                int n = n0 + tx * 4 + j;
                float v = acc[i][j] + bseq[n];
                v = v > 0.f ? v : 0.01f * v;
                partial[i] += v * w2[n];
            }
    }
    #pragma unroll
    for (int i = 0; i < 4; ++i) R[ty * 4 + i][tx] = partial[i];
    __syncthreads();
    if (tid < 64) {
        float s = 0.f;
        #pragma unroll
        for (int x = 0; x < 16; ++x) s += R[tid][x];
        s += b2[0];
        out[m0 + tid] = fmaxf(s, 0.f);
    }
}

// ---------------------------------------------------------------------------
extern "C" void kernel_launch(void* const* d_in, const int* in_sizes, int n_in,
                              void* d_out, int out_size, void* d_ws, size_t ws_size,
                              hipStream_t stream) {
    const float* enc_out = (const float*)d_in[0];
    const float* enc_hid = (const float*)d_in[1];
    const float* start   = (const float*)d_in[2];
    const float* W_l2h   = (const float*)d_in[3];
    const float* b_l2h   = (const float*)d_in[4];
    const float* W_l2h2  = (const float*)d_in[5];
    const float* b_l2h2  = (const float*)d_in[6];
    const float* W_emb   = (const float*)d_in[7];
    const float* b_emb   = (const float*)d_in[8];
    const float* W_ih    = (const float*)d_in[9];
    const float* W_hh    = (const float*)d_in[10];
    const float* b_ih    = (const float*)d_in[11];
    const float* b_hh    = (const float*)d_in[12];
    const float* W_out_p = (const float*)d_in[13];
    const float* b_out_p = (const float*)d_in[14];
    const float* W_seq   = (const float*)d_in[15];
    const float* b_seq   = (const float*)d_in[16];
    const float* W_seq2  = (const float*)d_in[17];
    const float* b_seq2  = (const float*)d_in[18];

    float* out = (float*)d_out;
    float* out_dec = out;                                   // [B, SEQ, O]
    float* out_hT  = out + (size_t)B_ * SEQ_ * O_;          // [1, B, H]
    float* out_cT  = out_hT + (size_t)B_ * H_;              // [1, B, H]
    float* out_num = out_cT + (size_t)B_ * H_;              // [B, TE, 1]

    char* w = (char*)d_ws;
    float* x0 = (float*)w;            w += 4096;
    float* hA = (float*)w;            w += (size_t)B_ * H_ * 4;
    float* hB = (float*)w;            w += (size_t)B_ * H_ * 4;
    float* cbuf = (float*)w;          w += (size_t)B_ * H_ * 4;
    __hip_bfloat16* hist = (__hip_bfloat16*)w;
    size_t base_used = (size_t)(w - (char*)d_ws);
    size_t need_hist = (size_t)SEQ_ * B_ * H_ * sizeof(__hip_bfloat16);
    bool use_hist = ws_size >= base_used + need_hist;

    // init: x0, h0 -> hA, c0 -> cbuf
    k_x0<<<dim3(2), dim3(256), 0, stream>>>(start, W_emb, b_emb, x0);
    dim3 g_init(H_ / 64, B_ / 64);
    k_proj_act<<<g_init, dim3(256), 0, stream>>>(enc_hid, W_l2h,  b_l2h,  hA,   B_, H_, L_, 1);
    k_proj_act<<<g_init, dim3(256), 0, stream>>>(enc_hid, W_l2h2, b_l2h2, cbuf, B_, H_, L_, 1);

    // LSTM: 100 steps
    dim3 g_lstm(H_ / 16, B_ / 64);
    for (int t = 0; t < SEQ_; ++t) {
        const float* hprev = (t & 1) ? hB : hA;
        float* hnext = (t & 1) ? hA : hB;
        const float* xs = (t == 0) ? x0 : hprev;
        int xstride = (t == 0) ? 0 : H_;
        __hip_bfloat16* ht = use_hist ? hist + (size_t)t * B_ * H_ : nullptr;
        k_lstm_step<<<g_lstm, dim3(256), 0, stream>>>(xs, xstride, hprev, W_ih, W_hh,
                                                      b_ih, b_hh, cbuf, hnext, ht);
        if (!use_hist) {
            k_y_step<<<dim3(O_ / 64, B_ / 64), dim3(256), 0, stream>>>(hnext, W_out_p, b_out_p,
                                                                       out_dec, t);
        }
    }
    if (use_hist) {
        k_out_proj<<<dim3(O_ / 64, (SEQ_ * B_) / 64), dim3(256), 0, stream>>>(hist, W_out_p,
                                                                              b_out_p, out_dec);
    }
    // final states: after t=99 (odd), h is in hA; c is in cbuf
    hipMemcpyAsync(out_hT, hA,   (size_t)B_ * H_ * 4, hipMemcpyDeviceToDevice, stream);
    hipMemcpyAsync(out_cT, cbuf, (size_t)B_ * H_ * 4, hipMemcpyDeviceToDevice, stream);

    // num head
    k_num<<<dim3((B_ * TE_) / 64), dim3(256), 0, stream>>>(enc_out, W_seq, b_seq,
                                                           W_seq2, b_seq2, out_num);
}

// Round 2
// 2099.628 us; speedup vs baseline: 3.8957x; 3.8957x over previous
//
#include <hip/hip_runtime.h>
#include <hip/hip_bf16.h>

#define B_   1024
#define H_   512
#define L_   256
#define O_   128
#define SEQ_ 100
#define TE_  200
#define RS   72   // LDS row stride (ushorts) for 64-wide bf16 tiles, +8 pad

typedef __attribute__((ext_vector_type(8))) short short8;
typedef __attribute__((ext_vector_type(4))) float f32x4;

__device__ __forceinline__ float sigmoidf_(float x) { return 1.f / (1.f + __expf(-x)); }
__device__ __forceinline__ float tanhf_(float x) { return 1.f - 2.f / (__expf(2.f * x) + 1.f); }
__device__ __forceinline__ unsigned short f2bf(float x) {
    union { float f; unsigned u; } c; c.f = x;
    unsigned r = c.u + 0x7fffu + ((c.u >> 16) & 1u);   // RNE
    return (unsigned short)(r >> 16);
}
__device__ __forceinline__ unsigned relu2bf(unsigned x) {
    unsigned hi = x & 0xFFFF0000u, lo = x & 0x0000FFFFu;
    if (x & 0x80000000u) hi = 0u;
    if (x & 0x00008000u) lo = 0u;
    return hi | lo;
}
__device__ __forceinline__ uint4 relu8bf(uint4 v) {
    v.x = relu2bf(v.x); v.y = relu2bf(v.y); v.z = relu2bf(v.z); v.w = relu2bf(v.w);
    return v;
}

// ---------------------------------------------------------------------------
// fp32 -> bf16 convert (n4 = count/4)
// ---------------------------------------------------------------------------
__global__ void k_cvt(const float* __restrict__ s, unsigned short* __restrict__ d, int n4) {
    int i = blockIdx.x * 256 + threadIdx.x;
    if (i < n4) {
        float4 v = ((const float4*)s)[i];
        ushort4 o; o.x = f2bf(v.x); o.y = f2bf(v.y); o.z = f2bf(v.z); o.w = f2bf(v.w);
        ((ushort4*)d)[i] = o;
    }
}

// ---------------------------------------------------------------------------
// Pack LSTM weights: Wcat[n'=j*4+g][k 0..1023] bf16 (k<512: W_ih, else W_hh),
// biasp[n'] = b_ih + b_hh. grid 2048 x 256.
// ---------------------------------------------------------------------------
__global__ void k_pack_w(const float* __restrict__ Wih, const float* __restrict__ Whh,
                         const float* __restrict__ bih, const float* __restrict__ bhh,
                         unsigned short* __restrict__ Wcat, float* __restrict__ biasp) {
    int np = blockIdx.x;              // 0..2047
    int j = np >> 2, g = np & 3;
    int sr = g * H_ + j;
    int t = threadIdx.x;
    const float* src = (t < 128) ? (Wih + (size_t)sr * H_) : (Whh + (size_t)sr * H_);
    int idx = (t < 128) ? t : (t - 128);
    float4 v = ((const float4*)src)[idx];
    ushort4 o; o.x = f2bf(v.x); o.y = f2bf(v.y); o.z = f2bf(v.z); o.w = f2bf(v.w);
    ((ushort4*)(Wcat + (size_t)np * 1024))[t] = o;     // dest k = t*4 (both halves)
    if (t == 0) biasp[np] = bih[sr] + bhh[sr];
}

// ---------------------------------------------------------------------------
// x0[j] = b_emb[j] + start . W_emb[j,:]  -> bf16
// ---------------------------------------------------------------------------
__global__ void k_x0(const float* __restrict__ start, const float* __restrict__ Wemb,
                     const float* __restrict__ bemb, unsigned short* __restrict__ x0) {
    int j = blockIdx.x * 256 + threadIdx.x;
    if (j < H_) {
        float s = bemb[j];
        const float* wp = Wemb + (size_t)j * O_;
        #pragma unroll 4
        for (int o = 0; o < O_; ++o) s += start[o] * wp[o];
        x0[j] = f2bf(s);
    }
}

// ---------------------------------------------------------------------------
// fp32 tiled init projection with leaky_relu; writes fp32 and/or bf16.
// M=1024 N=512 K=256 only — cheap.
// ---------------------------------------------------------------------------
__global__ __launch_bounds__(256) void k_proj_act(
    const float* __restrict__ A, const float* __restrict__ W,
    const float* __restrict__ bias, float* __restrict__ outf,
    unsigned short* __restrict__ outbf, int M, int N, int K)
{
    __shared__ __align__(16) float As[16][68];
    __shared__ __align__(16) float Bs[16][68];
    const int tid = threadIdx.x;
    const int tx = tid & 15, ty = tid >> 4;
    const int m0 = blockIdx.y * 64, n0 = blockIdx.x * 64;
    float acc[4][4] = {};
    for (int kt = 0; kt < K; kt += 16) {
        int m = tid >> 2, k4 = (tid & 3) * 4;
        float4 av = *(const float4*)(A + (size_t)(m0 + m) * K + kt + k4);
        As[k4 + 0][m] = av.x; As[k4 + 1][m] = av.y; As[k4 + 2][m] = av.z; As[k4 + 3][m] = av.w;
        float4 bv = *(const float4*)(W + (size_t)(n0 + m) * K + kt + k4);
        Bs[k4 + 0][m] = bv.x; Bs[k4 + 1][m] = bv.y; Bs[k4 + 2][m] = bv.z; Bs[k4 + 3][m] = bv.w;
        __syncthreads();
        #pragma unroll
        for (int kk = 0; kk < 16; ++kk) {
            float4 a = *(const float4*)&As[kk][ty * 4];
            float4 b = *(const float4*)&Bs[kk][tx * 4];
            float aa[4] = {a.x, a.y, a.z, a.w}, bb[4] = {b.x, b.y, b.z, b.w};
            #pragma unroll
            for (int i = 0; i < 4; ++i)
                #pragma unroll
                for (int j = 0; j < 4; ++j) acc[i][j] += aa[i] * bb[j];
        }
        __syncthreads();
    }
    #pragma unroll
    for (int i = 0; i < 4; ++i) {
        int m = m0 + ty * 4 + i;
        #pragma unroll
        for (int j = 0; j < 4; ++j) {
            int n = n0 + tx * 4 + j;
            float v = acc[i][j] + bias[n];
            v = v > 0.f ? v : 0.01f * v;
            if (outf)  outf[(size_t)m * N + n] = v;
            if (outbf) outbf[(size_t)m * N + n] = f2bf(v);
        }
    }
}

// ---------------------------------------------------------------------------
// MFMA LSTM step. Block 64 rows x 64 gate-cols (16 j's x 4 gates, packed).
// A = [relu(x) (k<512) ; h (k>=512)], both bf16. 4 waves, wave tile 32x32.
// ---------------------------------------------------------------------------
__global__ __launch_bounds__(256) void k_lstm_mfma(
    const unsigned short* __restrict__ xsrc, int x_stride,
    const unsigned short* __restrict__ hsrc,
    const unsigned short* __restrict__ Wcat,
    const float* __restrict__ biasp,
    float* __restrict__ c,
    unsigned short* __restrict__ hist_t,
    float* __restrict__ hT_out)
{
    __shared__ __align__(16) unsigned short As[64 * RS];
    __shared__ __align__(16) unsigned short Bs[64 * RS];
    __shared__ __align__(16) float Gt[64 * 69];
    const int tid = threadIdx.x;
    const int lane = tid & 63, w = tid >> 6;
    const int q = lane >> 4, ln = lane & 15;
    const int wrow = w & 1, wcol = w >> 1;
    const int m0 = blockIdx.y * 64, n0 = blockIdx.x * 64;
    const int r0 = tid >> 3, cc = (tid & 7) * 8;
    f32x4 acc[2][2] = {};
    for (int kt = 0; kt < 1024; kt += 64) {
        uint4 a0, a1, b0, b1;
        if (kt < 512) {
            a0 = *(const uint4*)(xsrc + (size_t)(m0 + r0) * x_stride + kt + cc);
            a1 = *(const uint4*)(xsrc + (size_t)(m0 + r0 + 32) * x_stride + kt + cc);
            a0 = relu8bf(a0); a1 = relu8bf(a1);
        } else {
            a0 = *(const uint4*)(hsrc + (size_t)(m0 + r0) * H_ + (kt - 512) + cc);
            a1 = *(const uint4*)(hsrc + (size_t)(m0 + r0 + 32) * H_ + (kt - 512) + cc);
        }
        b0 = *(const uint4*)(Wcat + (size_t)(n0 + r0) * 1024 + kt + cc);
        b1 = *(const uint4*)(Wcat + (size_t)(n0 + r0 + 32) * 1024 + kt + cc);
        __syncthreads();
        *(uint4*)&As[r0 * RS + cc] = a0;
        *(uint4*)&As[(r0 + 32) * RS + cc] = a1;
        *(uint4*)&Bs[r0 * RS + cc] = b0;
        *(uint4*)&Bs[(r0 + 32) * RS + cc] = b1;
        __syncthreads();
        #pragma unroll
        for (int kh = 0; kh < 2; ++kh) {
            short8 af0 = *(const short8*)&As[(wrow * 32 + ln) * RS + kh * 32 + q * 8];
            short8 af1 = *(const short8*)&As[(wrow * 32 + 16 + ln) * RS + kh * 32 + q * 8];
            short8 bf0 = *(const short8*)&Bs[(wcol * 32 + ln) * RS + kh * 32 + q * 8];
            short8 bf1 = *(const short8*)&Bs[(wcol * 32 + 16 + ln) * RS + kh * 32 + q * 8];
            acc[0][0] = __builtin_amdgcn_mfma_f32_16x16x32_bf16(af0, bf0, acc[0][0], 0, 0, 0);
            acc[0][1] = __builtin_amdgcn_mfma_f32_16x16x32_bf16(af0, bf1, acc[0][1], 0, 0, 0);
            acc[1][0] = __builtin_amdgcn_mfma_f32_16x16x32_bf16(af1, bf0, acc[1][0], 0, 0, 0);
            acc[1][1] = __builtin_amdgcn_mfma_f32_16x16x32_bf16(af1, bf1, acc[1][1], 0, 0, 0);
        }
    }
    // C layout: row=(lane>>4)*4+reg, col=lane&15 — stash full gate tile in LDS
    #pragma unroll
    for (int mt = 0; mt < 2; ++mt)
        #pragma unroll
        for (int nt = 0; nt < 2; ++nt)
            #pragma unroll
            for (int r = 0; r < 4; ++r)
                Gt[(wrow * 32 + mt * 16 + q * 4 + r) * 69 + wcol * 32 + nt * 16 + ln] = acc[mt][nt][r];
    __syncthreads();
    const int jj = tid & 15;
    const int j = (n0 >> 2) + jj;
    const float b_i = biasp[n0 + jj * 4 + 0];
    const float b_f = biasp[n0 + jj * 4 + 1];
    const float b_g = biasp[n0 + jj * 4 + 2];
    const float b_o = biasp[n0 + jj * 4 + 3];
    #pragma unroll
    for (int l = 0; l < 4; ++l) {
        int m = (tid >> 4) + l * 16;
        float iv = Gt[m * 69 + jj * 4 + 0] + b_i;
        float fv = Gt[m * 69 + jj * 4 + 1] + b_f;
        float gv = Gt[m * 69 + jj * 4 + 2] + b_g;
        float ov = Gt[m * 69 + jj * 4 + 3] + b_o;
        size_t off = (size_t)(m0 + m) * H_ + j;
        float cv = c[off];
        float cn = sigmoidf_(fv) * cv + sigmoidf_(iv) * tanhf_(gv);
        float hn = sigmoidf_(ov) * tanhf_(cn);
        c[off] = cn;
        hist_t[off] = f2bf(hn);
        if (hT_out) hT_out[off] = hn;
    }
}

// ---------------------------------------------------------------------------
// Output projection: out[b,t,o] = hist[t,b,:] . Wout[o,:] + bout[o].
// M=102400 (r = t*1024+b), N=128, K=512. Block 64x64.
// ---------------------------------------------------------------------------
__global__ __launch_bounds__(256) void k_outproj_mfma(
    const unsigned short* __restrict__ hist,
    const unsigned short* __restrict__ Wo,
    const float* __restrict__ bo,
    float* __restrict__ out)
{
    __shared__ __align__(16) unsigned short As[64 * RS];
    __shared__ __align__(16) unsigned short Bs[64 * RS];
    const int tid = threadIdx.x;
    const int lane = tid & 63, w = tid >> 6;
    const int q = lane >> 4, ln = lane & 15;
    const int wrow = w & 1, wcol = w >> 1;
    const int m0 = blockIdx.y * 64, n0 = blockIdx.x * 64;
    const int r0 = tid >> 3, cc = (tid & 7) * 8;
    f32x4 acc[2][2] = {};
    for (int kt = 0; kt < 512; kt += 64) {
        uint4 a0 = *(const uint4*)(hist + (size_t)(m0 + r0) * H_ + kt + cc);
        uint4 a1 = *(const uint4*)(hist + (size_t)(m0 + r0 + 32) * H_ + kt + cc);
        uint4 b0 = *(const uint4*)(Wo + (size_t)(n0 + r0) * H_ + kt + cc);
        uint4 b1 = *(const uint4*)(Wo + (size_t)(n0 + r0 + 32) * H_ + kt + cc);
        __syncthreads();
        *(uint4*)&As[r0 * RS + cc] = a0;
        *(uint4*)&As[(r0 + 32) * RS + cc] = a1;
        *(uint4*)&Bs[r0 * RS + cc] = b0;
        *(uint4*)&Bs[(r0 + 32) * RS + cc] = b1;
        __syncthreads();
        #pragma unroll
        for (int kh = 0; kh < 2; ++kh) {
            short8 af0 = *(const short8*)&As[(wrow * 32 + ln) * RS + kh * 32 + q * 8];
            short8 af1 = *(const short8*)&As[(wrow * 32 + 16 + ln) * RS + kh * 32 + q * 8];
            short8 bf0 = *(const short8*)&Bs[(wcol * 32 + ln) * RS + kh * 32 + q * 8];
            short8 bf1 = *(const short8*)&Bs[(wcol * 32 + 16 + ln) * RS + kh * 32 + q * 8];
            acc[0][0] = __builtin_amdgcn_mfma_f32_16x16x32_bf16(af0, bf0, acc[0][0], 0, 0, 0);
            acc[0][1] = __builtin_amdgcn_mfma_f32_16x16x32_bf16(af0, bf1, acc[0][1], 0, 0, 0);
            acc[1][0] = __builtin_amdgcn_mfma_f32_16x16x32_bf16(af1, bf0, acc[1][0], 0, 0, 0);
            acc[1][1] = __builtin_amdgcn_mfma_f32_16x16x32_bf16(af1, bf1, acc[1][1], 0, 0, 0);
        }
    }
    #pragma unroll
    for (int mt = 0; mt < 2; ++mt)
        #pragma unroll
        for (int nt = 0; nt < 2; ++nt) {
            int n = n0 + wcol * 32 + nt * 16 + ln;
            float bv = bo[n];
            #pragma unroll
            for (int r = 0; r < 4; ++r) {
                int row = m0 + wrow * 32 + mt * 16 + q * 4 + r;
                int t = row >> 10, b = row & 1023;
                out[(size_t)b * (SEQ_ * O_) + t * O_ + n] = acc[mt][nt][r] + bv;
            }
        }
}

// ---------------------------------------------------------------------------
// num head: out[r] = relu(b2 + sum_n w2[n] * lrelu(bseq[n] + enc[r,:] . Wseq[n,:]))
// M=204800 rows, N=512 (8 chunks of 64), K=256. Block 64 rows.
// ---------------------------------------------------------------------------
__global__ __launch_bounds__(256) void k_num_mfma(
    const unsigned short* __restrict__ enc,
    const unsigned short* __restrict__ Wseq,
    const float* __restrict__ bseq,
    const float* __restrict__ w2,
    const float* __restrict__ b2,
    float* __restrict__ out)
{
    __shared__ __align__(16) unsigned short As[64 * RS];
    __shared__ __align__(16) unsigned short Bs[64 * RS];
    const int tid = threadIdx.x;
    const int lane = tid & 63, w = tid >> 6;
    const int q = lane >> 4, ln = lane & 15;
    const int wrow = w & 1, wcol = w >> 1;
    const int m0 = blockIdx.x * 64;
    const int r0 = tid >> 3, cc = (tid & 7) * 8;
    float partial[2][4] = {};
    for (int nc = 0; nc < 8; ++nc) {
        f32x4 acc[2][2] = {};
        for (int kt = 0; kt < 256; kt += 64) {
            uint4 a0 = *(const uint4*)(enc + (size_t)(m0 + r0) * L_ + kt + cc);
            uint4 a1 = *(const uint4*)(enc + (size_t)(m0 + r0 + 32) * L_ + kt + cc);
            uint4 b0 = *(const uint4*)(Wseq + (size_t)(nc * 64 + r0) * L_ + kt + cc);
            uint4 b1 = *(const uint4*)(Wseq + (size_t)(nc * 64 + r0 + 32) * L_ + kt + cc);
            __syncthreads();
            *(uint4*)&As[r0 * RS + cc] = a0;
            *(uint4*)&As[(r0 + 32) * RS + cc] = a1;
            *(uint4*)&Bs[r0 * RS + cc] = b0;
            *(uint4*)&Bs[(r0 + 32) * RS + cc] = b1;
            __syncthreads();
            #pragma unroll
            for (int kh = 0; kh < 2; ++kh) {
                short8 af0 = *(const short8*)&As[(wrow * 32 + ln) * RS + kh * 32 + q * 8];
                short8 af1 = *(const short8*)&As[(wrow * 32 + 16 + ln) * RS + kh * 32 + q * 8];
                short8 bf0 = *(const short8*)&Bs[(wcol * 32 + ln) * RS + kh * 32 + q * 8];
                short8 bf1 = *(const short8*)&Bs[(wcol * 32 + 16 + ln) * RS + kh * 32 + q * 8];
                acc[0][0] = __builtin_amdgcn_mfma_f32_16x16x32_bf16(af0, bf0, acc[0][0], 0, 0, 0);
                acc[0][1] = __builtin_amdgcn_mfma_f32_16x16x32_bf16(af0, bf1, acc[0][1], 0, 0, 0);
                acc[1][0] = __builtin_amdgcn_mfma_f32_16x16x32_bf16(af1, bf0, acc[1][0], 0, 0, 0);
                acc[1][1] = __builtin_amdgcn_mfma_f32_16x16x32_bf16(af1, bf1, acc[1][1], 0, 0, 0);
            }
        }
        #pragma unroll
        for (int nt = 0; nt < 2; ++nt) {
            int n = nc * 64 + wcol * 32 + nt * 16 + ln;
            float bs = bseq[n], wv = w2[n];
            #pragma unroll
            for (int mt = 0; mt < 2; ++mt)
                #pragma unroll
                for (int r = 0; r < 4; ++r) {
                    float v = acc[mt][nt][r] + bs;
                    v = v > 0.f ? v : 0.01f * v;
                    partial[mt][r] += v * wv;
                }
        }
    }
    __syncthreads();
    float* R = (float*)As;   // 64 x 33 floats = 8448 B <= 9216 B
    #pragma unroll
    for (int mt = 0; mt < 2; ++mt)
        #pragma unroll
        for (int r = 0; r < 4; ++r)
            R[(wrow * 32 + mt * 16 + q * 4 + r) * 33 + wcol * 16 + ln] = partial[mt][r];
    __syncthreads();
    if (tid < 64) {
        float s = b2[0];
        #pragma unroll 8
        for (int k2 = 0; k2 < 32; ++k2) s += R[tid * 33 + k2];
        out[m0 + tid] = fmaxf(s, 0.f);
    }
}

// ---------------------------------------------------------------------------
extern "C" void kernel_launch(void* const* d_in, const int* in_sizes, int n_in,
                              void* d_out, int out_size, void* d_ws, size_t ws_size,
                              hipStream_t stream) {
    const float* enc_out = (const float*)d_in[0];
    const float* enc_hid = (const float*)d_in[1];
    const float* start   = (const float*)d_in[2];
    const float* W_l2h   = (const float*)d_in[3];
    const float* b_l2h   = (const float*)d_in[4];
    const float* W_l2h2  = (const float*)d_in[5];
    const float* b_l2h2  = (const float*)d_in[6];
    const float* W_emb   = (const float*)d_in[7];
    const float* b_emb   = (const float*)d_in[8];
    const float* W_ih    = (const float*)d_in[9];
    const float* W_hh    = (const float*)d_in[10];
    const float* b_ih    = (const float*)d_in[11];
    const float* b_hh    = (const float*)d_in[12];
    const float* W_out_p = (const float*)d_in[13];
    const float* b_out_p = (const float*)d_in[14];
    const float* W_seq   = (const float*)d_in[15];
    const float* b_seq   = (const float*)d_in[16];
    const float* W_seq2  = (const float*)d_in[17];
    const float* b_seq2  = (const float*)d_in[18];

    float* out = (float*)d_out;
    float* out_dec = out;                                   // [B, SEQ, O]
    float* out_hT  = out + (size_t)B_ * SEQ_ * O_;          // [1, B, H]
    float* out_cT  = out_hT + (size_t)B_ * H_;              // [1, B, H]
    float* out_num = out_cT + (size_t)B_ * H_;              // [B, TE, 1]

    // ws layout — enc_bf and hist alias the same 100 MiB region (disjoint lifetimes:
    // k_num consumes enc_bf before the first LSTM step writes hist).
    char* w = (char*)d_ws;
    unsigned short* shared_bf = (unsigned short*)w;         // enc_bf OR hist
    w += (size_t)SEQ_ * B_ * H_ * 2;                        // 104,857,600 B (== 204800*256*2)
    float* cbuf = (float*)w;             w += (size_t)B_ * H_ * 4;
    unsigned short* h0_bf = (unsigned short*)w;  w += (size_t)B_ * H_ * 2;
    unsigned short* Wcat = (unsigned short*)w;   w += (size_t)2048 * 1024 * 2;
    float* biasp = (float*)w;            w += 2048 * 4;
    unsigned short* Wout_bf = (unsigned short*)w; w += (size_t)O_ * H_ * 2;
    unsigned short* Wseq_bf = (unsigned short*)w; w += (size_t)H_ * L_ * 2;
    unsigned short* x0_bf = (unsigned short*)w;   w += 4096;

    // ---- num head first (uses shared_bf as enc_bf) ----
    int enc4 = (B_ * TE_ * L_) / 4;
    k_cvt<<<dim3((enc4 + 255) / 256), dim3(256), 0, stream>>>(enc_out, shared_bf, enc4);
    k_cvt<<<dim3((H_ * L_ / 4 + 255) / 256), dim3(256), 0, stream>>>(W_seq, Wseq_bf, H_ * L_ / 4);
    k_num_mfma<<<dim3((B_ * TE_) / 64), dim3(256), 0, stream>>>(shared_bf, Wseq_bf, b_seq,
                                                                W_seq2, b_seq2, out_num);

    // ---- weight packing ----
    k_pack_w<<<dim3(2048), dim3(256), 0, stream>>>(W_ih, W_hh, b_ih, b_hh, Wcat, biasp);
    k_cvt<<<dim3((O_ * H_ / 4 + 255) / 256), dim3(256), 0, stream>>>(W_out_p, Wout_bf, O_ * H_ / 4);
    k_x0<<<dim3(2), dim3(256), 0, stream>>>(start, W_emb, b_emb, x0_bf);

    // ---- init h0 (bf16), c0 (fp32) ----
    dim3 g_init(H_ / 64, B_ / 64);
    k_proj_act<<<g_init, dim3(256), 0, stream>>>(enc_hid, W_l2h,  b_l2h,  nullptr, h0_bf, B_, H_, L_);
    k_proj_act<<<g_init, dim3(256), 0, stream>>>(enc_hid, W_l2h2, b_l2h2, cbuf, nullptr, B_, H_, L_);

    // ---- 100 LSTM steps (hist doubles as next-step input) ----
    unsigned short* hist = shared_bf;
    dim3 g_lstm(2048 / 64, B_ / 64);
    for (int t = 0; t < SEQ_; ++t) {
        const unsigned short* hprev = (t == 0) ? h0_bf : hist + (size_t)(t - 1) * B_ * H_;
        const unsigned short* xs = (t == 0) ? x0_bf : hprev;
        int xstr = (t == 0) ? 0 : H_;
        float* hT = (t == SEQ_ - 1) ? out_hT : nullptr;
        k_lstm_mfma<<<g_lstm, dim3(256), 0, stream>>>(xs, xstr, hprev, Wcat, biasp, cbuf,
                                                      hist + (size_t)t * B_ * H_, hT);
    }

    // ---- batched output projection ----
    k_outproj_mfma<<<dim3(O_ / 64, (SEQ_ * B_) / 64), dim3(256), 0, stream>>>(hist, Wout_bf,
                                                                              b_out_p, out_dec);
    // ---- final c ----
    hipMemcpyAsync(out_cT, cbuf, (size_t)B_ * H_ * 4, hipMemcpyDeviceToDevice, stream);
}

// Round 3
// 2057.650 us; speedup vs baseline: 3.9752x; 1.0204x over previous
//
#include <hip/hip_runtime.h>
#include <hip/hip_bf16.h>

#define B_   1024
#define H_   512
#define L_   256
#define O_   128
#define SEQ_ 100
#define TE_  200
#define RS   72    // LDS row stride (ushorts) for 64-wide bf16 tiles (+8 pad)
#define AR   264   // LDS row stride (ushorts) for 256-wide bf16 tiles (+8 pad)

typedef __attribute__((ext_vector_type(8))) short short8;
typedef __attribute__((ext_vector_type(4))) float f32x4;

__device__ __forceinline__ float sigmoidf_(float x) { return 1.f / (1.f + __expf(-x)); }
__device__ __forceinline__ float tanhf_(float x) { return 1.f - 2.f / (__expf(2.f * x) + 1.f); }
__device__ __forceinline__ unsigned short f2bf(float x) {
    union { float f; unsigned u; } c; c.f = x;
    unsigned r = c.u + 0x7fffu + ((c.u >> 16) & 1u);   // RNE
    return (unsigned short)(r >> 16);
}
__device__ __forceinline__ unsigned relu2bf(unsigned x) {
    unsigned hi = x & 0xFFFF0000u, lo = x & 0x0000FFFFu;
    if (x & 0x80000000u) hi = 0u;
    if (x & 0x00008000u) lo = 0u;
    return hi | lo;
}
__device__ __forceinline__ uint4 relu8bf(uint4 v) {
    v.x = relu2bf(v.x); v.y = relu2bf(v.y); v.z = relu2bf(v.z); v.w = relu2bf(v.w);
    return v;
}

// ---------------------------------------------------------------------------
// fp32 -> bf16 convert (n4 = count/4) — used for small weights only
// ---------------------------------------------------------------------------
__global__ void k_cvt(const float* __restrict__ s, unsigned short* __restrict__ d, int n4) {
    int i = blockIdx.x * 256 + threadIdx.x;
    if (i < n4) {
        float4 v = ((const float4*)s)[i];
        ushort4 o; o.x = f2bf(v.x); o.y = f2bf(v.y); o.z = f2bf(v.z); o.w = f2bf(v.w);
        ((ushort4*)d)[i] = o;
    }
}

// ---------------------------------------------------------------------------
// Pack LSTM weights: Wcat[n'=j*4+g][k 0..1023] bf16 (k<512: W_ih, else W_hh),
// biasp[n'] = b_ih + b_hh.
// ---------------------------------------------------------------------------
__global__ void k_pack_w(const float* __restrict__ Wih, const float* __restrict__ Whh,
                         const float* __restrict__ bih, const float* __restrict__ bhh,
                         unsigned short* __restrict__ Wcat, float* __restrict__ biasp) {
    int np = blockIdx.x;              // 0..2047
    int j = np >> 2, g = np & 3;
    int sr = g * H_ + j;
    int t = threadIdx.x;
    const float* src = (t < 128) ? (Wih + (size_t)sr * H_) : (Whh + (size_t)sr * H_);
    int idx = (t < 128) ? t : (t - 128);
    float4 v = ((const float4*)src)[idx];
    ushort4 o; o.x = f2bf(v.x); o.y = f2bf(v.y); o.z = f2bf(v.z); o.w = f2bf(v.w);
    ((ushort4*)(Wcat + (size_t)np * 1024))[t] = o;
    if (t == 0) biasp[np] = bih[sr] + bhh[sr];
}

// ---------------------------------------------------------------------------
// x0[j] = b_emb[j] + start . W_emb[j,:]  -> bf16
// ---------------------------------------------------------------------------
__global__ void k_x0(const float* __restrict__ start, const float* __restrict__ Wemb,
                     const float* __restrict__ bemb, unsigned short* __restrict__ x0) {
    int j = blockIdx.x * 256 + threadIdx.x;
    if (j < H_) {
        float s = bemb[j];
        const float* wp = Wemb + (size_t)j * O_;
        #pragma unroll 4
        for (int o = 0; o < O_; ++o) s += start[o] * wp[o];
        x0[j] = f2bf(s);
    }
}

// ---------------------------------------------------------------------------
// fp32 tiled init projection with leaky_relu; writes fp32 and/or bf16.
// ---------------------------------------------------------------------------
__global__ __launch_bounds__(256) void k_proj_act(
    const float* __restrict__ A, const float* __restrict__ W,
    const float* __restrict__ bias, float* __restrict__ outf,
    unsigned short* __restrict__ outbf, int M, int N, int K)
{
    __shared__ __align__(16) float As[16][68];
    __shared__ __align__(16) float Bs[16][68];
    const int tid = threadIdx.x;
    const int tx = tid & 15, ty = tid >> 4;
    const int m0 = blockIdx.y * 64, n0 = blockIdx.x * 64;
    float acc[4][4] = {};
    for (int kt = 0; kt < K; kt += 16) {
        int m = tid >> 2, k4 = (tid & 3) * 4;
        float4 av = *(const float4*)(A + (size_t)(m0 + m) * K + kt + k4);
        As[k4 + 0][m] = av.x; As[k4 + 1][m] = av.y; As[k4 + 2][m] = av.z; As[k4 + 3][m] = av.w;
        float4 bv = *(const float4*)(W + (size_t)(n0 + m) * K + kt + k4);
        Bs[k4 + 0][m] = bv.x; Bs[k4 + 1][m] = bv.y; Bs[k4 + 2][m] = bv.z; Bs[k4 + 3][m] = bv.w;
        __syncthreads();
        #pragma unroll
        for (int kk = 0; kk < 16; ++kk) {
            float4 a = *(const float4*)&As[kk][ty * 4];
            float4 b = *(const float4*)&Bs[kk][tx * 4];
            float aa[4] = {a.x, a.y, a.z, a.w}, bb[4] = {b.x, b.y, b.z, b.w};
            #pragma unroll
            for (int i = 0; i < 4; ++i)
                #pragma unroll
                for (int j = 0; j < 4; ++j) acc[i][j] += aa[i] * bb[j];
        }
        __syncthreads();
    }
    #pragma unroll
    for (int i = 0; i < 4; ++i) {
        int m = m0 + ty * 4 + i;
        #pragma unroll
        for (int j = 0; j < 4; ++j) {
            int n = n0 + tx * 4 + j;
            float v = acc[i][j] + bias[n];
            v = v > 0.f ? v : 0.01f * v;
            if (outf)  outf[(size_t)m * N + n] = v;
            if (outbf) outbf[(size_t)m * N + n] = f2bf(v);
        }
    }
}

// ---------------------------------------------------------------------------
// MFMA LSTM step with register-prefetch pipeline.
// Block 64 rows x 64 gate-cols; 4 waves 2x2; wave 32x32 (2x2 of 16x16x32).
// ---------------------------------------------------------------------------
__global__ __launch_bounds__(256) void k_lstm_mfma(
    const unsigned short* __restrict__ xsrc, int x_stride,
    const unsigned short* __restrict__ hsrc,
    const unsigned short* __restrict__ Wcat,
    const float* __restrict__ biasp,
    float* __restrict__ c,
    unsigned short* __restrict__ hist_t,
    float* __restrict__ hT_out)
{
    __shared__ __align__(16) unsigned short As[64 * RS];
    __shared__ __align__(16) unsigned short Bs[64 * RS];
    __shared__ __align__(16) float Gt[64 * 69];
    const int tid = threadIdx.x;
    const int lane = tid & 63, w = tid >> 6;
    const int q = lane >> 4, ln = lane & 15;
    const int wrow = w & 1, wcol = w >> 1;
    const int m0 = blockIdx.y * 64, n0 = blockIdx.x * 64;
    const int r0 = tid >> 3, cc = (tid & 7) * 8;
    f32x4 acc[2][2] = {};
    uint4 a0, a1, b0, b1;

    // prologue: load kt = 0
    {
        a0 = relu8bf(*(const uint4*)(xsrc + (size_t)(m0 + r0) * x_stride + cc));
        a1 = relu8bf(*(const uint4*)(xsrc + (size_t)(m0 + r0 + 32) * x_stride + cc));
        b0 = *(const uint4*)(Wcat + (size_t)(n0 + r0) * 1024 + cc);
        b1 = *(const uint4*)(Wcat + (size_t)(n0 + r0 + 32) * 1024 + cc);
    }
    for (int it = 0; it < 16; ++it) {
        __syncthreads();
        *(uint4*)&As[r0 * RS + cc] = a0;
        *(uint4*)&As[(r0 + 32) * RS + cc] = a1;
        *(uint4*)&Bs[r0 * RS + cc] = b0;
        *(uint4*)&Bs[(r0 + 32) * RS + cc] = b1;
        __syncthreads();
        // prefetch next tile (overlaps MFMA below)
        if (it < 15) {
            int kt = (it + 1) * 64;
            if (kt < 512) {
                a0 = relu8bf(*(const uint4*)(xsrc + (size_t)(m0 + r0) * x_stride + kt + cc));
                a1 = relu8bf(*(const uint4*)(xsrc + (size_t)(m0 + r0 + 32) * x_stride + kt + cc));
            } else {
                a0 = *(const uint4*)(hsrc + (size_t)(m0 + r0) * H_ + (kt - 512) + cc);
                a1 = *(const uint4*)(hsrc + (size_t)(m0 + r0 + 32) * H_ + (kt - 512) + cc);
            }
            b0 = *(const uint4*)(Wcat + (size_t)(n0 + r0) * 1024 + kt + cc);
            b1 = *(const uint4*)(Wcat + (size_t)(n0 + r0 + 32) * 1024 + kt + cc);
        }
        #pragma unroll
        for (int kh = 0; kh < 2; ++kh) {
            short8 af0 = *(const short8*)&As[(wrow * 32 + ln) * RS + kh * 32 + q * 8];
            short8 af1 = *(const short8*)&As[(wrow * 32 + 16 + ln) * RS + kh * 32 + q * 8];
            short8 bf0 = *(const short8*)&Bs[(wcol * 32 + ln) * RS + kh * 32 + q * 8];
            short8 bf1 = *(const short8*)&Bs[(wcol * 32 + 16 + ln) * RS + kh * 32 + q * 8];
            acc[0][0] = __builtin_amdgcn_mfma_f32_16x16x32_bf16(af0, bf0, acc[0][0], 0, 0, 0);
            acc[0][1] = __builtin_amdgcn_mfma_f32_16x16x32_bf16(af0, bf1, acc[0][1], 0, 0, 0);
            acc[1][0] = __builtin_amdgcn_mfma_f32_16x16x32_bf16(af1, bf0, acc[1][0], 0, 0, 0);
            acc[1][1] = __builtin_amdgcn_mfma_f32_16x16x32_bf16(af1, bf1, acc[1][1], 0, 0, 0);
        }
    }
    // C layout: row=(lane>>4)*4+reg, col=lane&15
    #pragma unroll
    for (int mt = 0; mt < 2; ++mt)
        #pragma unroll
        for (int nt = 0; nt < 2; ++nt)
            #pragma unroll
            for (int r = 0; r < 4; ++r)
                Gt[(wrow * 32 + mt * 16 + q * 4 + r) * 69 + wcol * 32 + nt * 16 + ln] = acc[mt][nt][r];
    __syncthreads();
    const int jj = tid & 15;
    const int j = (n0 >> 2) + jj;
    const float b_i = biasp[n0 + jj * 4 + 0];
    const float b_f = biasp[n0 + jj * 4 + 1];
    const float b_g = biasp[n0 + jj * 4 + 2];
    const float b_o = biasp[n0 + jj * 4 + 3];
    #pragma unroll
    for (int l = 0; l < 4; ++l) {
        int m = (tid >> 4) + l * 16;
        float iv = Gt[m * 69 + jj * 4 + 0] + b_i;
        float fv = Gt[m * 69 + jj * 4 + 1] + b_f;
        float gv = Gt[m * 69 + jj * 4 + 2] + b_g;
        float ov = Gt[m * 69 + jj * 4 + 3] + b_o;
        size_t off = (size_t)(m0 + m) * H_ + j;
        float cv = c[off];
        float cn = sigmoidf_(fv) * cv + sigmoidf_(iv) * tanhf_(gv);
        float hn = sigmoidf_(ov) * tanhf_(cn);
        c[off] = cn;
        hist_t[off] = f2bf(hn);
        if (hT_out) hT_out[off] = hn;
    }
}

// ---------------------------------------------------------------------------
// Output projection with register-prefetch. M=102400, N=128, K=512.
// ---------------------------------------------------------------------------
__global__ __launch_bounds__(256) void k_outproj_mfma(
    const unsigned short* __restrict__ hist,
    const unsigned short* __restrict__ Wo,
    const float* __restrict__ bo,
    float* __restrict__ out)
{
    __shared__ __align__(16) unsigned short As[64 * RS];
    __shared__ __align__(16) unsigned short Bs[64 * RS];
    const int tid = threadIdx.x;
    const int lane = tid & 63, w = tid >> 6;
    const int q = lane >> 4, ln = lane & 15;
    const int wrow = w & 1, wcol = w >> 1;
    const int m0 = blockIdx.y * 64, n0 = blockIdx.x * 64;
    const int r0 = tid >> 3, cc = (tid & 7) * 8;
    f32x4 acc[2][2] = {};
    uint4 a0 = *(const uint4*)(hist + (size_t)(m0 + r0) * H_ + cc);
    uint4 a1 = *(const uint4*)(hist + (size_t)(m0 + r0 + 32) * H_ + cc);
    uint4 b0 = *(const uint4*)(Wo + (size_t)(n0 + r0) * H_ + cc);
    uint4 b1 = *(const uint4*)(Wo + (size_t)(n0 + r0 + 32) * H_ + cc);
    for (int it = 0; it < 8; ++it) {
        __syncthreads();
        *(uint4*)&As[r0 * RS + cc] = a0;
        *(uint4*)&As[(r0 + 32) * RS + cc] = a1;
        *(uint4*)&Bs[r0 * RS + cc] = b0;
        *(uint4*)&Bs[(r0 + 32) * RS + cc] = b1;
        __syncthreads();
        if (it < 7) {
            int kt = (it + 1) * 64;
            a0 = *(const uint4*)(hist + (size_t)(m0 + r0) * H_ + kt + cc);
            a1 = *(const uint4*)(hist + (size_t)(m0 + r0 + 32) * H_ + kt + cc);
            b0 = *(const uint4*)(Wo + (size_t)(n0 + r0) * H_ + kt + cc);
            b1 = *(const uint4*)(Wo + (size_t)(n0 + r0 + 32) * H_ + kt + cc);
        }
        #pragma unroll
        for (int kh = 0; kh < 2; ++kh) {
            short8 af0 = *(const short8*)&As[(wrow * 32 + ln) * RS + kh * 32 + q * 8];
            short8 af1 = *(const short8*)&As[(wrow * 32 + 16 + ln) * RS + kh * 32 + q * 8];
            short8 bf0 = *(const short8*)&Bs[(wcol * 32 + ln) * RS + kh * 32 + q * 8];
            short8 bf1 = *(const short8*)&Bs[(wcol * 32 + 16 + ln) * RS + kh * 32 + q * 8];
            acc[0][0] = __builtin_amdgcn_mfma_f32_16x16x32_bf16(af0, bf0, acc[0][0], 0, 0, 0);
            acc[0][1] = __builtin_amdgcn_mfma_f32_16x16x32_bf16(af0, bf1, acc[0][1], 0, 0, 0);
            acc[1][0] = __builtin_amdgcn_mfma_f32_16x16x32_bf16(af1, bf0, acc[1][0], 0, 0, 0);
            acc[1][1] = __builtin_amdgcn_mfma_f32_16x16x32_bf16(af1, bf1, acc[1][1], 0, 0, 0);
        }
    }
    #pragma unroll
    for (int mt = 0; mt < 2; ++mt)
        #pragma unroll
        for (int nt = 0; nt < 2; ++nt) {
            int n = n0 + wcol * 32 + nt * 16 + ln;
            float bv = bo[n];
            #pragma unroll
            for (int r = 0; r < 4; ++r) {
                int row = m0 + wrow * 32 + mt * 16 + q * 4 + r;
                int t = row >> 10, b = row & 1023;
                out[(size_t)b * (SEQ_ * O_) + t * O_ + n] = acc[mt][nt][r] + bv;
            }
        }
}

// ---------------------------------------------------------------------------
// num head, fused fp32->bf16 A staging (once per block), B chunks from L2.
// out[r] = relu(b2 + sum_n w2[n]*lrelu(bseq[n] + enc[r,:].Wseq[n,:]))
// ---------------------------------------------------------------------------
__global__ __launch_bounds__(256) void k_num_mfma(
    const float* __restrict__ enc,
    const unsigned short* __restrict__ Wseq,
    const float* __restrict__ bseq,
    const float* __restrict__ w2,
    const float* __restrict__ b2,
    float* __restrict__ out)
{
    __shared__ __align__(16) unsigned short As[64 * AR];
    __shared__ __align__(16) unsigned short Bs[64 * AR];
    const int tid = threadIdx.x;
    const int lane = tid & 63, w = tid >> 6;
    const int q = lane >> 4, ln = lane & 15;
    const int wrow = w & 1, wcol = w >> 1;
    const int m0 = blockIdx.x * 64;

    // stage A once: 64 rows x 256 cols fp32 -> bf16. Coalesced flat float4 loads.
    {
        const float* base = enc + (size_t)m0 * L_;
        #pragma unroll 4
        for (int it = 0; it < 16; ++it) {
            int flat = it * 1024 + tid * 4;           // float index in tile
            int row = flat >> 8, col = flat & 255;
            float4 v = *(const float4*)(base + flat);
            ushort4 o; o.x = f2bf(v.x); o.y = f2bf(v.y); o.z = f2bf(v.z); o.w = f2bf(v.w);
            *(ushort4*)&As[row * AR + col] = o;
        }
    }
    float partial[2][4] = {};
    for (int nc = 0; nc < 8; ++nc) {
        __syncthreads();   // protect Bs (and As on first iter) from in-flight reads
        // stage B chunk: 64 n-rows x 256 k, bf16, coalesced uint4
        {
            const unsigned short* bb = Wseq + (size_t)nc * 64 * L_;
            #pragma unroll
            for (int it = 0; it < 8; ++it) {
                int flat = it * 2048 + tid * 8;       // ushort index in chunk
                int row = flat >> 8, col = flat & 255;
                *(uint4*)&Bs[row * AR + col] = *(const uint4*)(bb + flat);
            }
        }
        __syncthreads();
        f32x4 acc[2][2] = {};
        #pragma unroll
        for (int kt = 0; kt < 8; ++kt) {
            short8 af0 = *(const short8*)&As[(wrow * 32 + ln) * AR + kt * 32 + q * 8];
            short8 af1 = *(const short8*)&As[(wrow * 32 + 16 + ln) * AR + kt * 32 + q * 8];
            short8 bf0 = *(const short8*)&Bs[(wcol * 32 + ln) * AR + kt * 32 + q * 8];
            short8 bf1 = *(const short8*)&Bs[(wcol * 32 + 16 + ln) * AR + kt * 32 + q * 8];
            acc[0][0] = __builtin_amdgcn_mfma_f32_16x16x32_bf16(af0, bf0, acc[0][0], 0, 0, 0);
            acc[0][1] = __builtin_amdgcn_mfma_f32_16x16x32_bf16(af0, bf1, acc[0][1], 0, 0, 0);
            acc[1][0] = __builtin_amdgcn_mfma_f32_16x16x32_bf16(af1, bf0, acc[1][0], 0, 0, 0);
            acc[1][1] = __builtin_amdgcn_mfma_f32_16x16x32_bf16(af1, bf1, acc[1][1], 0, 0, 0);
        }
        #pragma unroll
        for (int nt = 0; nt < 2; ++nt) {
            int n = nc * 64 + wcol * 32 + nt * 16 + ln;
            float bs = bseq[n], wv = w2[n];
            #pragma unroll
            for (int mt = 0; mt < 2; ++mt)
                #pragma unroll
                for (int r = 0; r < 4; ++r) {
                    float v = acc[mt][nt][r] + bs;
                    v = v > 0.f ? v : 0.01f * v;
                    partial[mt][r] += v * wv;
                }
        }
    }
    __syncthreads();
    float* R = (float*)As;   // 64 x 33 floats, overlays A staging
    #pragma unroll
    for (int mt = 0; mt < 2; ++mt)
        #pragma unroll
        for (int r = 0; r < 4; ++r)
            R[(wrow * 32 + mt * 16 + q * 4 + r) * 33 + wcol * 16 + ln] = partial[mt][r];
    __syncthreads();
    if (tid < 64) {
        float s = b2[0];
        #pragma unroll 8
        for (int k2 = 0; k2 < 32; ++k2) s += R[tid * 33 + k2];
        out[m0 + tid] = fmaxf(s, 0.f);
    }
}

// ---------------------------------------------------------------------------
extern "C" void kernel_launch(void* const* d_in, const int* in_sizes, int n_in,
                              void* d_out, int out_size, void* d_ws, size_t ws_size,
                              hipStream_t stream) {
    const float* enc_out = (const float*)d_in[0];
    const float* enc_hid = (const float*)d_in[1];
    const float* start   = (const float*)d_in[2];
    const float* W_l2h   = (const float*)d_in[3];
    const float* b_l2h   = (const float*)d_in[4];
    const float* W_l2h2  = (const float*)d_in[5];
    const float* b_l2h2  = (const float*)d_in[6];
    const float* W_emb   = (const float*)d_in[7];
    const float* b_emb   = (const float*)d_in[8];
    const float* W_ih    = (const float*)d_in[9];
    const float* W_hh    = (const float*)d_in[10];
    const float* b_ih    = (const float*)d_in[11];
    const float* b_hh    = (const float*)d_in[12];
    const float* W_out_p = (const float*)d_in[13];
    const float* b_out_p = (const float*)d_in[14];
    const float* W_seq   = (const float*)d_in[15];
    const float* b_seq   = (const float*)d_in[16];
    const float* W_seq2  = (const float*)d_in[17];
    const float* b_seq2  = (const float*)d_in[18];

    float* out = (float*)d_out;
    float* out_dec = out;                                   // [B, SEQ, O]
    float* out_hT  = out + (size_t)B_ * SEQ_ * O_;          // [1, B, H]
    float* out_cT  = out_hT + (size_t)B_ * H_;              // [1, B, H]
    float* out_num = out_cT + (size_t)B_ * H_;              // [B, TE, 1]

    char* w = (char*)d_ws;
    unsigned short* hist = (unsigned short*)w;   w += (size_t)SEQ_ * B_ * H_ * 2;
    float* cbuf = (float*)w;                     w += (size_t)B_ * H_ * 4;
    unsigned short* h0_bf = (unsigned short*)w;  w += (size_t)B_ * H_ * 2;
    unsigned short* Wcat = (unsigned short*)w;   w += (size_t)2048 * 1024 * 2;
    float* biasp = (float*)w;                    w += 2048 * 4;
    unsigned short* Wout_bf = (unsigned short*)w; w += (size_t)O_ * H_ * 2;
    unsigned short* Wseq_bf = (unsigned short*)w; w += (size_t)H_ * L_ * 2;
    unsigned short* x0_bf = (unsigned short*)w;   w += 4096;

    // ---- weight prep ----
    k_pack_w<<<dim3(2048), dim3(256), 0, stream>>>(W_ih, W_hh, b_ih, b_hh, Wcat, biasp);
    k_cvt<<<dim3((O_ * H_ / 4 + 255) / 256), dim3(256), 0, stream>>>(W_out_p, Wout_bf, O_ * H_ / 4);
    k_cvt<<<dim3((H_ * L_ / 4 + 255) / 256), dim3(256), 0, stream>>>(W_seq, Wseq_bf, H_ * L_ / 4);
    k_x0<<<dim3(2), dim3(256), 0, stream>>>(start, W_emb, b_emb, x0_bf);

    // ---- init h0 (bf16), c0 (fp32) ----
    dim3 g_init(H_ / 64, B_ / 64);
    k_proj_act<<<g_init, dim3(256), 0, stream>>>(enc_hid, W_l2h,  b_l2h,  nullptr, h0_bf, B_, H_, L_);
    k_proj_act<<<g_init, dim3(256), 0, stream>>>(enc_hid, W_l2h2, b_l2h2, cbuf, nullptr, B_, H_, L_);

    // ---- 100 LSTM steps ----
    dim3 g_lstm(2048 / 64, B_ / 64);
    for (int t = 0; t < SEQ_; ++t) {
        const unsigned short* hprev = (t == 0) ? h0_bf : hist + (size_t)(t - 1) * B_ * H_;
        const unsigned short* xs = (t == 0) ? x0_bf : hprev;
        int xstr = (t == 0) ? 0 : H_;
        float* hT = (t == SEQ_ - 1) ? out_hT : nullptr;
        k_lstm_mfma<<<g_lstm, dim3(256), 0, stream>>>(xs, xstr, hprev, Wcat, biasp, cbuf,
                                                      hist + (size_t)t * B_ * H_, hT);
    }

    // ---- batched output projection ----
    k_outproj_mfma<<<dim3(O_ / 64, (SEQ_ * B_) / 64), dim3(256), 0, stream>>>(hist, Wout_bf,
                                                                              b_out_p, out_dec);
    // ---- num head (reads enc fp32 directly) ----
    k_num_mfma<<<dim3((B_ * TE_) / 64), dim3(256), 0, stream>>>(enc_out, Wseq_bf, b_seq,
                                                                W_seq2, b_seq2, out_num);
    // ---- final c ----
    hipMemcpyAsync(out_cT, cbuf, (size_t)B_ * H_ * 4, hipMemcpyDeviceToDevice, stream);
}